// Round 3
// baseline (474.706 us; speedup 1.0000x reference)
//
#include <hip/hip_runtime.h>
#include <hip/hip_bf16.h>

// 2-layer GIN, pull-mode aggregation.
// CSR build via two-level binning:
//   coarse: bin edges by dst>>6 into ~1563 buckets (packed u32 = (dst&63)<<18 | src)
//   fine:   one WG per bucket counting-sorts 64 nodes entirely in LDS.
// Requires n_nodes < 2^18 (pack uses 18-bit src id). Here n_nodes = 100000.
// N_EDGES=1600000, D=64, fp32.

#define D 64
#define ROWS_PER_BLOCK 32
#define NPB 64        // nodes per coarse bucket
#define FCAP 2048     // fine-sort LDS edge capacity (expected ~1024/bucket)
#define HIST_EPB 16   // edges per thread in coarse_hist

__global__ void zero_int(int* __restrict__ p, int n) {
    int i = blockIdx.x * blockDim.x + threadIdx.x;
    if (i < n) p[i] = 0;
}

// Per-block LDS histogram of coarse bucket ids, flushed with global atomics.
__global__ __launch_bounds__(256) void coarse_hist(const int* __restrict__ dst,
                                                   int* __restrict__ hist,
                                                   int n_edges, int nb) {
    extern __shared__ int lh[];
    for (int i = threadIdx.x; i < nb; i += 256) lh[i] = 0;
    __syncthreads();
    int base = blockIdx.x * (256 * HIST_EPB);
#pragma unroll
    for (int k = 0; k < HIST_EPB; ++k) {
        int e = base + k * 256 + threadIdx.x;
        if (e < n_edges) atomicAdd(&lh[dst[e] >> 6], 1);
    }
    __syncthreads();
    for (int i = threadIdx.x; i < nb; i += 256) {
        int v = lh[i];
        if (v) atomicAdd(&hist[i], v);
    }
}

// Single-block exclusive scan of the ~1563 bucket counts.
// hist may alias ccursor (read-before-write ordering below).
__global__ __launch_bounds__(256) void coarse_scan(const int* __restrict__ hist,
                                                   int* __restrict__ cstart,
                                                   int* __restrict__ ccursor,
                                                   int nb, int n_edges) {
    __shared__ int tsum[256];
    int tid = threadIdx.x;
    int per = (nb + 255) / 256;
    int base = tid * per;
    int s = 0;
    for (int i = 0; i < per; ++i) {
        int idx = base + i;
        if (idx < nb) s += hist[idx];
    }
    tsum[tid] = s;
    __syncthreads();
    for (int off = 1; off < 256; off <<= 1) {
        int v = (tid >= off) ? tsum[tid - off] : 0;
        __syncthreads();
        tsum[tid] += v;
        __syncthreads();
    }
    int run = (tid == 0) ? 0 : tsum[tid - 1];
    for (int i = 0; i < per; ++i) {
        int idx = base + i;
        if (idx < nb) {
            int h = hist[idx];      // read BEFORE writing (alias-safe)
            cstart[idx] = run;
            ccursor[idx] = run;
            run += h;
        }
    }
    if (tid == 255) cstart[nb] = n_edges;
}

// Scatter packed edges into coarse buckets. Per-bucket write streams are
// sequential -> near-full-line writebacks (~6.4 MB, not 100+).
__global__ void coarse_scatter(const int* __restrict__ src, const int* __restrict__ dst,
                               int* __restrict__ ccursor, unsigned* __restrict__ tmp,
                               int n_edges) {
    int e = blockIdx.x * blockDim.x + threadIdx.x;
    if (e < n_edges) {
        int d = dst[e];
        int pos = atomicAdd(&ccursor[d >> 6], 1);
        tmp[pos] = ((unsigned)(d & (NPB - 1)) << 18) | (unsigned)src[e];
    }
}

// One WG per coarse bucket: LDS counting sort over its 64 nodes.
// Writes esrc (coalesced) and offs for nodes [b*64, b*64+64] (covers offs[n_nodes]).
__global__ __launch_bounds__(256) void fine_sort(const unsigned* __restrict__ tmp,
                                                 const int* __restrict__ cstart,
                                                 int* __restrict__ esrc,
                                                 int* __restrict__ offs,
                                                 int n_nodes) {
    __shared__ unsigned ledge[FCAP];
    __shared__ int lout[FCAP];
    __shared__ int lcnt[NPB], lofs_excl[NPB], lcur[NPB];

    int b = blockIdx.x;
    int tid = threadIdx.x;
    int base = cstart[b];
    int cnt = cstart[b + 1] - base;

    if (tid < NPB) lcnt[tid] = 0;
    __syncthreads();

    bool fits = (cnt <= FCAP);
    if (fits) {
        for (int i = tid; i < cnt; i += 256) {
            unsigned p = tmp[base + i];
            ledge[i] = p;
            atomicAdd(&lcnt[p >> 18], 1);
        }
    } else {  // fallback: no LDS staging (correct for any degree distribution)
        for (int i = tid; i < cnt; i += 256) atomicAdd(&lcnt[tmp[base + i] >> 18], 1);
    }
    __syncthreads();

    if (tid < NPB) {   // 64-lane shfl scan (wave 0)
        int own = lcnt[tid];
        int v = own;
        for (int off = 1; off < NPB; off <<= 1) {
            int u = __shfl_up(v, off);
            if (tid >= off) v += u;
        }
        int excl = v - own;
        lofs_excl[tid] = excl;
        lcur[tid] = excl;
        int node = b * NPB + tid;
        if (node <= n_nodes) offs[node] = base + excl;
    }
    __syncthreads();

    if (fits) {
        for (int i = tid; i < cnt; i += 256) {
            unsigned p = ledge[i];
            int pos = atomicAdd(&lcur[p >> 18], 1);
            lout[pos] = (int)(p & 0x3FFFFu);
        }
        __syncthreads();
        for (int i = tid; i < cnt; i += 256) esrc[base + i] = lout[i];
    } else {
        for (int i = tid; i < cnt; i += 256) {
            unsigned p = tmp[base + i];
            int pos = atomicAdd(&lcur[p >> 18], 1);
            esrc[base + pos] = (int)(p & 0x3FFFFu);
        }
    }
}

// Pull aggregation: 4 lanes per dst node; each lane owns 4 float4 (64B line).
// acc starts at h[n] (folds the (1+eps)*h self-term, eps=0).
__global__ void gin_agg(const float4* __restrict__ h, const int* __restrict__ offs,
                        const int* __restrict__ esrc, float4* __restrict__ agg,
                        int n_nodes) {
    int t = blockIdx.x * blockDim.x + threadIdx.x;
    int n = t >> 2;
    if (n >= n_nodes) return;
    int c = (t & 3) * 4;   // starting float4 index within the 16-float4 row
    int beg = offs[n];
    int end = offs[n + 1];
    const float4* row = h + (size_t)n * 16 + c;
    float4 a0 = row[0], a1 = row[1], a2 = row[2], a3 = row[3];
#pragma unroll 2
    for (int i = beg; i < end; ++i) {
        const float4* r = h + (size_t)esrc[i] * 16 + c;
        float4 v0 = r[0], v1 = r[1], v2 = r[2], v3 = r[3];
        a0.x += v0.x; a0.y += v0.y; a0.z += v0.z; a0.w += v0.w;
        a1.x += v1.x; a1.y += v1.y; a1.z += v1.z; a1.w += v1.w;
        a2.x += v2.x; a2.y += v2.y; a2.z += v2.z; a2.w += v2.w;
        a3.x += v3.x; a3.y += v3.y; a3.z += v3.z; a3.w += v3.w;
    }
    float4* o = agg + (size_t)n * 16 + c;
    o[0] = a0; o[1] = a1; o[2] = a2; o[3] = a3;
}

// out = relu(hs @ W + b). Safe in-place: rows staged in LDS first.
__global__ __launch_bounds__(256) void gin_mlp(const float* __restrict__ hs,
                                               const float* __restrict__ W,
                                               const float* __restrict__ b,
                                               float* __restrict__ out,
                                               int n_nodes) {
    __shared__ float Wl[D * D];
    __shared__ float bl[D];
    __shared__ float rows[ROWS_PER_BLOCK][D];

    int tid = threadIdx.x;

    const float4* W4 = (const float4*)W;
    float4* Wl4 = (float4*)Wl;
#pragma unroll
    for (int i = 0; i < 4; ++i) Wl4[tid + 256 * i] = W4[tid + 256 * i];
    if (tid < D / 4) ((float4*)bl)[tid] = ((const float4*)b)[tid];

    size_t row0 = (size_t)blockIdx.x * ROWS_PER_BLOCK;
    const float4* hs4 = (const float4*)(hs + row0 * D);
    float4* rows4 = (float4*)rows;
#pragma unroll
    for (int i = 0; i < 2; ++i) rows4[tid + 256 * i] = hs4[tid + 256 * i];

    __syncthreads();

    int lane = tid & 63;
    int w = tid >> 6;

    float acc[8];
#pragma unroll
    for (int r = 0; r < 8; ++r) acc[r] = bl[lane];

#pragma unroll
    for (int k = 0; k < D; ++k) {
        float wv = Wl[k * D + lane];
#pragma unroll
        for (int r = 0; r < 8; ++r)
            acc[r] = fmaf(rows[w * 8 + r][k], wv, acc[r]);
    }

#pragma unroll
    for (int r = 0; r < 8; ++r) {
        float v = acc[r] > 0.0f ? acc[r] : 0.0f;
        out[(row0 + (size_t)w * 8 + r) * D + lane] = v;
    }
}

extern "C" void kernel_launch(void* const* d_in, const int* in_sizes, int n_in,
                              void* d_out, int out_size, void* d_ws, size_t ws_size,
                              hipStream_t stream) {
    const float* x   = (const float*)d_in[0];
    const int*   src = (const int*)d_in[1];
    const int*   dst = (const int*)d_in[2];
    const float* W1  = (const float*)d_in[3];
    const float* b1  = (const float*)d_in[4];
    const float* W2  = (const float*)d_in[5];
    const float* b2  = (const float*)d_in[6];
    float* out = (float*)d_out;

    const int n_nodes = in_sizes[0] / D;
    const int n_edges = in_sizes[1];
    const int nb = (n_nodes + NPB - 1) / NPB;   // coarse buckets

    // workspace: A | offs | cstart | ccursor | tmp | esrc
    float*    A       = (float*)d_ws;                        // [n_nodes*64]
    int*      offs    = (int*)(A + (size_t)n_nodes * D);     // n_nodes+1
    int*      cstart  = offs + (n_nodes + 1);                // nb+1
    int*      ccursor = cstart + (nb + 1);                   // nb (also coarse hist)
    unsigned* tmp     = (unsigned*)(ccursor + nb);           // n_edges
    int*      esrc    = (int*)(tmp + n_edges);               // n_edges

    const int eb = (n_edges + 255) / 256;
    const int hist_blocks = (n_edges + 256 * HIST_EPB - 1) / (256 * HIST_EPB);
    const int agg_blocks = (n_nodes * 4 + 255) / 256;
    const int mlp_blocks = (n_nodes + ROWS_PER_BLOCK - 1) / ROWS_PER_BLOCK;
    const size_t hist_smem = (size_t)nb * sizeof(int);

    // ---- CSR build ----
    zero_int<<<(nb + 255) / 256, 256, 0, stream>>>(ccursor, nb);
    coarse_hist<<<hist_blocks, 256, hist_smem, stream>>>(dst, ccursor, n_edges, nb);
    coarse_scan<<<1, 256, 0, stream>>>(ccursor, cstart, ccursor, nb, n_edges);
    coarse_scatter<<<eb, 256, 0, stream>>>(src, dst, ccursor, tmp, n_edges);
    fine_sort<<<nb, 256, 0, stream>>>(tmp, cstart, esrc, offs, n_nodes);

    // ---- layer 1: agg(x) -> A, mlp in-place A -> A ----
    gin_agg<<<agg_blocks, 256, 0, stream>>>((const float4*)x, offs, esrc, (float4*)A, n_nodes);
    gin_mlp<<<mlp_blocks, 256, 0, stream>>>(A, W1, b1, A, n_nodes);

    // ---- layer 2: agg(h1) -> out, mlp in-place out -> out ----
    gin_agg<<<agg_blocks, 256, 0, stream>>>((const float4*)A, offs, esrc, (float4*)out, n_nodes);
    gin_mlp<<<mlp_blocks, 256, 0, stream>>>(out, W2, b2, out, n_nodes);
}

// Round 4
// 344.797 us; speedup vs baseline: 1.3768x; 1.3768x over previous
//
#include <hip/hip_runtime.h>
#include <hip/hip_bf16.h>

// 2-layer GIN, pull-mode aggregation.
// CSR build = deterministic radix partition (no global atomics):
//   k1: per-chunk LDS histogram over 196 super-buckets (512 nodes each)
//   k2: single-WG exclusive scan of the [bucket][chunk] histogram matrix
//   k3: per-chunk scatter with LDS cursors -> tmp (packed (dst&511)<<18|src)
//   k4: per-super-bucket node-level counting sort -> esrc + offs
//       (scatter stays inside a WG-owned 32KB window: no cross-XCD ping-pong)
// Requires n_nodes < 2^18. Here N=100000, E=1600000, D=64, fp32.

#define D 64
#define ROWS_PER_BLOCK 32
#define CHSZ 8192      // edges per chunk (k1/k3)
#define NPBS 512       // nodes per super-bucket
#define SBSHIFT 9      // log2(NPBS)
#define MAXNBS 256     // static LDS cap on #super-buckets (needs n_nodes <= 131072)

__device__ inline void f4add(float4& a, const float4& b) {
    a.x += b.x; a.y += b.y; a.z += b.z; a.w += b.w;
}

// ---------------- CSR build ----------------

__global__ __launch_bounds__(256) void k1_hist(const int* __restrict__ dst,
                                               int* __restrict__ hist,
                                               int n_edges, int nch, int nbs) {
    __shared__ int lh[MAXNBS];
    for (int i = threadIdx.x; i < nbs; i += 256) lh[i] = 0;
    __syncthreads();
    int base = blockIdx.x * CHSZ;
    int lim = min(CHSZ, n_edges - base);
    for (int k = threadIdx.x; k < lim; k += 256)
        atomicAdd(&lh[dst[base + k] >> SBSHIFT], 1);
    __syncthreads();
    for (int i = threadIdx.x; i < nbs; i += 256)
        hist[i * nch + blockIdx.x] = lh[i];   // bucket-major
}

// In-place exclusive scan of hist[nbs*nch]; also emits sstart[b] (bucket bases).
__global__ __launch_bounds__(256) void k2_scan(int* __restrict__ hist,
                                               int* __restrict__ sstart,
                                               int total_n, int nch, int nbs, int n_edges) {
    __shared__ int tsum[256];
    int tid = threadIdx.x;
    int per = (total_n + 255) / 256;
    int b0 = tid * per;
    int s = 0;
    for (int i = 0; i < per; ++i) {
        int idx = b0 + i;
        if (idx < total_n) s += hist[idx];
    }
    tsum[tid] = s;
    __syncthreads();
    for (int off = 1; off < 256; off <<= 1) {
        int v = (tid >= off) ? tsum[tid - off] : 0;
        __syncthreads();
        tsum[tid] += v;
        __syncthreads();
    }
    int run = (tid == 0) ? 0 : tsum[tid - 1];
    for (int i = 0; i < per; ++i) {
        int idx = b0 + i;
        if (idx < total_n) {
            int h = hist[idx];
            hist[idx] = run;
            if (idx % nch == 0) sstart[idx / nch] = run;
            run += h;
        }
    }
    if (tid == 255) sstart[nbs] = n_edges;
}

__global__ __launch_bounds__(256) void k3_scatter(const int* __restrict__ src,
                                                  const int* __restrict__ dst,
                                                  const int* __restrict__ hist,
                                                  unsigned* __restrict__ tmp,
                                                  int n_edges, int nch, int nbs) {
    __shared__ int lcur[MAXNBS];
    int c = blockIdx.x;
    for (int i = threadIdx.x; i < nbs; i += 256) lcur[i] = hist[i * nch + c];
    __syncthreads();
    int base = c * CHSZ;
    int lim = min(CHSZ, n_edges - base);
    for (int k = threadIdx.x; k < lim; k += 256) {
        int d = dst[base + k];
        int s = src[base + k];
        int pos = atomicAdd(&lcur[d >> SBSHIFT], 1);
        tmp[pos] = ((unsigned)(d & (NPBS - 1)) << 18) | (unsigned)s;
    }
}

// One WG per super-bucket: node-level counting sort in a WG-owned window.
__global__ __launch_bounds__(256) void k4_fine(const unsigned* __restrict__ tmp,
                                               const int* __restrict__ sstart,
                                               int* __restrict__ esrc,
                                               int* __restrict__ offs,
                                               int n_nodes) {
    __shared__ int lcnt[NPBS];
    __shared__ int lcur[NPBS];
    __shared__ int tsum[256];

    int b = blockIdx.x;
    int tid = threadIdx.x;
    int base = sstart[b];
    int cnt = sstart[b + 1] - base;

    lcnt[tid] = 0; lcnt[tid + 256] = 0;
    __syncthreads();

    for (int i = tid; i < cnt; i += 256)
        atomicAdd(&lcnt[tmp[base + i] >> 18], 1);
    __syncthreads();

    // exclusive scan of 512 counts: per-thread pair + Hillis over 256 sums
    int a0 = lcnt[2 * tid], a1 = lcnt[2 * tid + 1];
    tsum[tid] = a0 + a1;
    __syncthreads();
    for (int off = 1; off < 256; off <<= 1) {
        int v = (tid >= off) ? tsum[tid - off] : 0;
        __syncthreads();
        tsum[tid] += v;
        __syncthreads();
    }
    int ex = (tid == 0) ? 0 : tsum[tid - 1];
    lcur[2 * tid] = ex;
    lcur[2 * tid + 1] = ex + a0;

    int node = b * NPBS + 2 * tid;
    if (node <= n_nodes) offs[node] = base + ex;
    if (node + 1 <= n_nodes) offs[node + 1] = base + ex + a0;
    __syncthreads();

    for (int i = tid; i < cnt; i += 256) {
        unsigned p = tmp[base + i];
        int pos = atomicAdd(&lcur[p >> 18], 1);
        esrc[base + pos] = (int)(p & 0x3FFFFu);
    }
}

// ---------------- per-layer kernels ----------------

// Pull aggregation: 4 lanes/node, lane c owns one 64B line of the row.
// Edges processed 4 at a time -> 16 float4 gathers in flight per thread.
// acc starts at h[n] (folds the (1+eps)*h self-term, eps=0).
__global__ __launch_bounds__(256) void gin_agg(const float4* __restrict__ h,
                                               const int* __restrict__ offs,
                                               const int* __restrict__ esrc,
                                               float4* __restrict__ agg,
                                               int n_nodes) {
    int t = blockIdx.x * 256 + threadIdx.x;
    int n = t >> 2;
    if (n >= n_nodes) return;
    int c = (t & 3) * 4;
    const float4* row = h + (size_t)n * 16 + c;
    float4 a0 = row[0], a1 = row[1], a2 = row[2], a3 = row[3];
    int i = offs[n];
    int end = offs[n + 1];
    for (; i + 4 <= end; i += 4) {
        int s0 = esrc[i], s1 = esrc[i + 1], s2 = esrc[i + 2], s3 = esrc[i + 3];
        const float4* r0 = h + (size_t)s0 * 16 + c;
        const float4* r1 = h + (size_t)s1 * 16 + c;
        const float4* r2 = h + (size_t)s2 * 16 + c;
        const float4* r3 = h + (size_t)s3 * 16 + c;
        float4 b00 = r0[0], b01 = r0[1], b02 = r0[2], b03 = r0[3];
        float4 b10 = r1[0], b11 = r1[1], b12 = r1[2], b13 = r1[3];
        float4 b20 = r2[0], b21 = r2[1], b22 = r2[2], b23 = r2[3];
        float4 b30 = r3[0], b31 = r3[1], b32 = r3[2], b33 = r3[3];
        f4add(a0, b00); f4add(a1, b01); f4add(a2, b02); f4add(a3, b03);
        f4add(a0, b10); f4add(a1, b11); f4add(a2, b12); f4add(a3, b13);
        f4add(a0, b20); f4add(a1, b21); f4add(a2, b22); f4add(a3, b23);
        f4add(a0, b30); f4add(a1, b31); f4add(a2, b32); f4add(a3, b33);
    }
    for (; i < end; ++i) {
        const float4* r = h + (size_t)esrc[i] * 16 + c;
        f4add(a0, r[0]); f4add(a1, r[1]); f4add(a2, r[2]); f4add(a3, r[3]);
    }
    float4* o = agg + (size_t)n * 16 + c;
    o[0] = a0; o[1] = a1; o[2] = a2; o[3] = a3;
}

// out = relu(hs @ W + b). Safe in-place: rows staged in LDS first.
__global__ __launch_bounds__(256) void gin_mlp(const float* __restrict__ hs,
                                               const float* __restrict__ W,
                                               const float* __restrict__ b,
                                               float* __restrict__ out,
                                               int n_nodes) {
    __shared__ float Wl[D * D];
    __shared__ float bl[D];
    __shared__ float rows[ROWS_PER_BLOCK][D];

    int tid = threadIdx.x;

    const float4* W4 = (const float4*)W;
    float4* Wl4 = (float4*)Wl;
#pragma unroll
    for (int i = 0; i < 4; ++i) Wl4[tid + 256 * i] = W4[tid + 256 * i];
    if (tid < D / 4) ((float4*)bl)[tid] = ((const float4*)b)[tid];

    size_t row0 = (size_t)blockIdx.x * ROWS_PER_BLOCK;
    const float4* hs4 = (const float4*)(hs + row0 * D);
    float4* rows4 = (float4*)rows;
#pragma unroll
    for (int i = 0; i < 2; ++i) rows4[tid + 256 * i] = hs4[tid + 256 * i];

    __syncthreads();

    int lane = tid & 63;
    int w = tid >> 6;

    float acc[8];
#pragma unroll
    for (int r = 0; r < 8; ++r) acc[r] = bl[lane];

#pragma unroll
    for (int k = 0; k < D; ++k) {
        float wv = Wl[k * D + lane];
#pragma unroll
        for (int r = 0; r < 8; ++r)
            acc[r] = fmaf(rows[w * 8 + r][k], wv, acc[r]);
    }

#pragma unroll
    for (int r = 0; r < 8; ++r) {
        float v = acc[r] > 0.0f ? acc[r] : 0.0f;
        out[(row0 + (size_t)w * 8 + r) * D + lane] = v;
    }
}

extern "C" void kernel_launch(void* const* d_in, const int* in_sizes, int n_in,
                              void* d_out, int out_size, void* d_ws, size_t ws_size,
                              hipStream_t stream) {
    const float* x   = (const float*)d_in[0];
    const int*   src = (const int*)d_in[1];
    const int*   dst = (const int*)d_in[2];
    const float* W1  = (const float*)d_in[3];
    const float* b1  = (const float*)d_in[4];
    const float* W2  = (const float*)d_in[5];
    const float* b2  = (const float*)d_in[6];
    float* out = (float*)d_out;

    const int n_nodes = in_sizes[0] / D;
    const int n_edges = in_sizes[1];
    const int nch = (n_edges + CHSZ - 1) / CHSZ;     // 196
    const int nbs = (n_nodes + NPBS - 1) / NPBS;     // 196

    // workspace: A | offs | sstart | hist | tmp | esrc  (~39 MB)
    float*    A      = (float*)d_ws;                      // [n_nodes*64]
    int*      offs   = (int*)(A + (size_t)n_nodes * D);   // n_nodes+1
    int*      sstart = offs + (n_nodes + 1);              // nbs+1
    int*      hist   = sstart + (nbs + 1);                // nbs*nch
    unsigned* tmp    = (unsigned*)(hist + nbs * nch);     // n_edges
    int*      esrc   = (int*)(tmp + n_edges);             // n_edges

    const int agg_blocks = (n_nodes * 4 + 255) / 256;
    const int mlp_blocks = (n_nodes + ROWS_PER_BLOCK - 1) / ROWS_PER_BLOCK;

    // ---- CSR build (deterministic, no global atomics) ----
    k1_hist<<<nch, 256, 0, stream>>>(dst, hist, n_edges, nch, nbs);
    k2_scan<<<1, 256, 0, stream>>>(hist, sstart, nbs * nch, nch, nbs, n_edges);
    k3_scatter<<<nch, 256, 0, stream>>>(src, dst, hist, tmp, n_edges, nch, nbs);
    k4_fine<<<nbs, 256, 0, stream>>>(tmp, sstart, esrc, offs, n_nodes);

    // ---- layer 1: agg(x) -> A, mlp in-place A -> A ----
    gin_agg<<<agg_blocks, 256, 0, stream>>>((const float4*)x, offs, esrc, (float4*)A, n_nodes);
    gin_mlp<<<mlp_blocks, 256, 0, stream>>>(A, W1, b1, A, n_nodes);

    // ---- layer 2: agg(h1) -> out, mlp in-place out -> out ----
    gin_agg<<<agg_blocks, 256, 0, stream>>>((const float4*)A, offs, esrc, (float4*)out, n_nodes);
    gin_mlp<<<mlp_blocks, 256, 0, stream>>>(out, W2, b2, out, n_nodes);
}

// Round 5
// 264.463 us; speedup vs baseline: 1.7950x; 1.3038x over previous
//
#include <hip/hip_runtime.h>
#include <hip/hip_bf16.h>

// 2-layer GIN, pull-mode aggregation.
// CSR build = deterministic radix partition (no global atomics):
//   k1:  per-chunk LDS histogram over 196 super-buckets (512 nodes each)
//   k2a: per-bucket row sums       (196 blocks-worth of wave reductions)
//   k2b: single tiny scan of 196 bucket totals -> sstart
//   k2c: per-bucket row scan (exclusive, + sstart[b]) in-place in hist
//   k3:  per-chunk scatter with LDS cursors -> tmp (packed (dst&511)<<18|src)
//   k4:  per-super-bucket node-level counting sort -> esrc + offs
// Requires n_nodes < 2^18. Here N=100000, E=1600000, D=64, fp32.

#define D 64
#define ROWS_PER_BLOCK 32
#define CHSZ 8192      // edges per chunk (k1/k3)
#define NPBS 512       // nodes per super-bucket
#define SBSHIFT 9      // log2(NPBS)
#define MAXNBS 256     // static LDS cap on #super-buckets (needs n_nodes <= 131072)
#define MAXNCH 512     // static LDS cap on #chunks in k2c (needs n_edges <= 4.2M)

__device__ inline void f4add(float4& a, const float4& b) {
    a.x += b.x; a.y += b.y; a.z += b.z; a.w += b.w;
}

// ---------------- CSR build ----------------

__global__ __launch_bounds__(256) void k1_hist(const int* __restrict__ dst,
                                               int* __restrict__ hist,
                                               int n_edges, int nch, int nbs) {
    __shared__ int lh[MAXNBS];
    for (int i = threadIdx.x; i < nbs; i += 256) lh[i] = 0;
    __syncthreads();
    int base = blockIdx.x * CHSZ;
    int lim = min(CHSZ, n_edges - base);
    for (int k = threadIdx.x; k < lim; k += 256)
        atomicAdd(&lh[dst[base + k] >> SBSHIFT], 1);
    __syncthreads();
    for (int i = threadIdx.x; i < nbs; i += 256)
        hist[i * nch + blockIdx.x] = lh[i];   // bucket-major
}

// 4 rows per block, 64 lanes reduce one row of nch counts.
__global__ __launch_bounds__(256) void k2a_rowsum(const int* __restrict__ hist,
                                                  int* __restrict__ total,
                                                  int nch, int nbs) {
    int w = threadIdx.x >> 6;          // wave in block
    int lane = threadIdx.x & 63;
    int b = blockIdx.x * 4 + w;
    if (b >= nbs) return;
    const int* row = hist + (size_t)b * nch;
    int s = 0;
    for (int c = lane; c < nch; c += 64) s += row[c];
#pragma unroll
    for (int off = 32; off > 0; off >>= 1) s += __shfl_down(s, off);
    if (lane == 0) total[b] = s;
}

// Single tiny WG: exclusive scan of nbs (<=256) totals -> sstart.
__global__ __launch_bounds__(256) void k2b_scan(const int* __restrict__ total,
                                                int* __restrict__ sstart,
                                                int nbs, int n_edges) {
    __shared__ int t[256];
    int tid = threadIdx.x;
    t[tid] = (tid < nbs) ? total[tid] : 0;
    __syncthreads();
    for (int off = 1; off < 256; off <<= 1) {
        int v = (tid >= off) ? t[tid - off] : 0;
        __syncthreads();
        t[tid] += v;
        __syncthreads();
    }
    if (tid < nbs) sstart[tid] = (tid == 0) ? 0 : t[tid - 1];
    if (tid == 0) sstart[nbs] = n_edges;
}

// One block per bucket: exclusive scan of its row (+ sstart[b]), in place.
__global__ __launch_bounds__(256) void k2c_rowscan(int* __restrict__ hist,
                                                   const int* __restrict__ sstart,
                                                   int nch, int nbs) {
    __shared__ int t[MAXNCH];
    int b = blockIdx.x;
    int tid = threadIdx.x;
    int* row = hist + (size_t)b * nch;
    int nround = (nch + 255) & ~255;
    for (int i = tid; i < nround; i += 256) t[i] = (i < nch) ? row[i] : 0;
    __syncthreads();
    for (int off = 1; off < nround; off <<= 1) {
        int v[MAXNCH / 256];
        for (int i = tid, j = 0; i < nround; i += 256, ++j)
            v[j] = (i >= off) ? t[i - off] : 0;
        __syncthreads();
        for (int i = tid, j = 0; i < nround; i += 256, ++j) t[i] += v[j];
        __syncthreads();
    }
    int base = sstart[b];
    for (int i = tid; i < nch; i += 256)
        row[i] = base + ((i == 0) ? 0 : t[i - 1]);
}

__global__ __launch_bounds__(256) void k3_scatter(const int* __restrict__ src,
                                                  const int* __restrict__ dst,
                                                  const int* __restrict__ hist,
                                                  unsigned* __restrict__ tmp,
                                                  int n_edges, int nch, int nbs) {
    __shared__ int lcur[MAXNBS];
    int c = blockIdx.x;
    for (int i = threadIdx.x; i < nbs; i += 256) lcur[i] = hist[i * nch + c];
    __syncthreads();
    int base = c * CHSZ;
    int lim = min(CHSZ, n_edges - base);
    for (int k = threadIdx.x; k < lim; k += 256) {
        int d = dst[base + k];
        int s = src[base + k];
        int pos = atomicAdd(&lcur[d >> SBSHIFT], 1);
        tmp[pos] = ((unsigned)(d & (NPBS - 1)) << 18) | (unsigned)s;
    }
}

// One WG per super-bucket: node-level counting sort in a WG-owned window.
__global__ __launch_bounds__(256) void k4_fine(const unsigned* __restrict__ tmp,
                                               const int* __restrict__ sstart,
                                               int* __restrict__ esrc,
                                               int* __restrict__ offs,
                                               int n_nodes) {
    __shared__ int lcnt[NPBS];
    __shared__ int lcur[NPBS];
    __shared__ int tsum[256];

    int b = blockIdx.x;
    int tid = threadIdx.x;
    int base = sstart[b];
    int cnt = sstart[b + 1] - base;

    lcnt[tid] = 0; lcnt[tid + 256] = 0;
    __syncthreads();

    for (int i = tid; i < cnt; i += 256)
        atomicAdd(&lcnt[tmp[base + i] >> 18], 1);
    __syncthreads();

    int a0 = lcnt[2 * tid], a1 = lcnt[2 * tid + 1];
    tsum[tid] = a0 + a1;
    __syncthreads();
    for (int off = 1; off < 256; off <<= 1) {
        int v = (tid >= off) ? tsum[tid - off] : 0;
        __syncthreads();
        tsum[tid] += v;
        __syncthreads();
    }
    int ex = (tid == 0) ? 0 : tsum[tid - 1];
    lcur[2 * tid] = ex;
    lcur[2 * tid + 1] = ex + a0;

    int node = b * NPBS + 2 * tid;
    if (node <= n_nodes) offs[node] = base + ex;
    if (node + 1 <= n_nodes) offs[node + 1] = base + ex + a0;
    __syncthreads();

    for (int i = tid; i < cnt; i += 256) {
        unsigned p = tmp[base + i];
        int pos = atomicAdd(&lcur[p >> 18], 1);
        esrc[base + pos] = (int)(p & 0x3FFFFu);
    }
}

// ---------------- per-layer kernels ----------------

// Pull aggregation: 4 lanes/node, lane c owns one 64B line of the row.
// Edges processed 4 at a time -> 16 float4 gathers in flight per thread.
__global__ __launch_bounds__(256) void gin_agg(const float4* __restrict__ h,
                                               const int* __restrict__ offs,
                                               const int* __restrict__ esrc,
                                               float4* __restrict__ agg,
                                               int n_nodes) {
    int t = blockIdx.x * 256 + threadIdx.x;
    int n = t >> 2;
    if (n >= n_nodes) return;
    int c = (t & 3) * 4;
    const float4* row = h + (size_t)n * 16 + c;
    float4 a0 = row[0], a1 = row[1], a2 = row[2], a3 = row[3];
    int i = offs[n];
    int end = offs[n + 1];
    for (; i + 4 <= end; i += 4) {
        int s0 = esrc[i], s1 = esrc[i + 1], s2 = esrc[i + 2], s3 = esrc[i + 3];
        const float4* r0 = h + (size_t)s0 * 16 + c;
        const float4* r1 = h + (size_t)s1 * 16 + c;
        const float4* r2 = h + (size_t)s2 * 16 + c;
        const float4* r3 = h + (size_t)s3 * 16 + c;
        float4 b00 = r0[0], b01 = r0[1], b02 = r0[2], b03 = r0[3];
        float4 b10 = r1[0], b11 = r1[1], b12 = r1[2], b13 = r1[3];
        float4 b20 = r2[0], b21 = r2[1], b22 = r2[2], b23 = r2[3];
        float4 b30 = r3[0], b31 = r3[1], b32 = r3[2], b33 = r3[3];
        f4add(a0, b00); f4add(a1, b01); f4add(a2, b02); f4add(a3, b03);
        f4add(a0, b10); f4add(a1, b11); f4add(a2, b12); f4add(a3, b13);
        f4add(a0, b20); f4add(a1, b21); f4add(a2, b22); f4add(a3, b23);
        f4add(a0, b30); f4add(a1, b31); f4add(a2, b32); f4add(a3, b33);
    }
    for (; i < end; ++i) {
        const float4* r = h + (size_t)esrc[i] * 16 + c;
        f4add(a0, r[0]); f4add(a1, r[1]); f4add(a2, r[2]); f4add(a3, r[3]);
    }
    float4* o = agg + (size_t)n * 16 + c;
    o[0] = a0; o[1] = a1; o[2] = a2; o[3] = a3;
}

// out = relu(hs @ W + b). Safe in-place: rows staged in LDS first.
__global__ __launch_bounds__(256) void gin_mlp(const float* __restrict__ hs,
                                               const float* __restrict__ W,
                                               const float* __restrict__ b,
                                               float* __restrict__ out,
                                               int n_nodes) {
    __shared__ float Wl[D * D];
    __shared__ float bl[D];
    __shared__ float rows[ROWS_PER_BLOCK][D];

    int tid = threadIdx.x;

    const float4* W4 = (const float4*)W;
    float4* Wl4 = (float4*)Wl;
#pragma unroll
    for (int i = 0; i < 4; ++i) Wl4[tid + 256 * i] = W4[tid + 256 * i];
    if (tid < D / 4) ((float4*)bl)[tid] = ((const float4*)b)[tid];

    size_t row0 = (size_t)blockIdx.x * ROWS_PER_BLOCK;
    const float4* hs4 = (const float4*)(hs + row0 * D);
    float4* rows4 = (float4*)rows;
#pragma unroll
    for (int i = 0; i < 2; ++i) rows4[tid + 256 * i] = hs4[tid + 256 * i];

    __syncthreads();

    int lane = tid & 63;
    int w = tid >> 6;

    float acc[8];
#pragma unroll
    for (int r = 0; r < 8; ++r) acc[r] = bl[lane];

#pragma unroll
    for (int k = 0; k < D; ++k) {
        float wv = Wl[k * D + lane];
#pragma unroll
        for (int r = 0; r < 8; ++r)
            acc[r] = fmaf(rows[w * 8 + r][k], wv, acc[r]);
    }

#pragma unroll
    for (int r = 0; r < 8; ++r) {
        float v = acc[r] > 0.0f ? acc[r] : 0.0f;
        out[(row0 + (size_t)w * 8 + r) * D + lane] = v;
    }
}

extern "C" void kernel_launch(void* const* d_in, const int* in_sizes, int n_in,
                              void* d_out, int out_size, void* d_ws, size_t ws_size,
                              hipStream_t stream) {
    const float* x   = (const float*)d_in[0];
    const int*   src = (const int*)d_in[1];
    const int*   dst = (const int*)d_in[2];
    const float* W1  = (const float*)d_in[3];
    const float* b1  = (const float*)d_in[4];
    const float* W2  = (const float*)d_in[5];
    const float* b2  = (const float*)d_in[6];
    float* out = (float*)d_out;

    const int n_nodes = in_sizes[0] / D;
    const int n_edges = in_sizes[1];
    const int nch = (n_edges + CHSZ - 1) / CHSZ;     // 196
    const int nbs = (n_nodes + NPBS - 1) / NPBS;     // 196

    // workspace: A | offs | sstart | total | hist | tmp | esrc  (~39 MB)
    float*    A      = (float*)d_ws;                      // [n_nodes*64]
    int*      offs   = (int*)(A + (size_t)n_nodes * D);   // n_nodes+1
    int*      sstart = offs + (n_nodes + 1);              // nbs+1
    int*      total  = sstart + (nbs + 1);                // nbs
    int*      hist   = total + nbs;                       // nbs*nch
    unsigned* tmp    = (unsigned*)(hist + (size_t)nbs * nch);  // n_edges
    int*      esrc   = (int*)(tmp + n_edges);             // n_edges

    const int agg_blocks = (n_nodes * 4 + 255) / 256;
    const int mlp_blocks = (n_nodes + ROWS_PER_BLOCK - 1) / ROWS_PER_BLOCK;

    // ---- CSR build (deterministic, no global atomics) ----
    k1_hist<<<nch, 256, 0, stream>>>(dst, hist, n_edges, nch, nbs);
    k2a_rowsum<<<(nbs + 3) / 4, 256, 0, stream>>>(hist, total, nch, nbs);
    k2b_scan<<<1, 256, 0, stream>>>(total, sstart, nbs, n_edges);
    k2c_rowscan<<<nbs, 256, 0, stream>>>(hist, sstart, nch, nbs);
    k3_scatter<<<nch, 256, 0, stream>>>(src, dst, hist, tmp, n_edges, nch, nbs);
    k4_fine<<<nbs, 256, 0, stream>>>(tmp, sstart, esrc, offs, n_nodes);

    // ---- layer 1: agg(x) -> A, mlp in-place A -> A ----
    gin_agg<<<agg_blocks, 256, 0, stream>>>((const float4*)x, offs, esrc, (float4*)A, n_nodes);
    gin_mlp<<<mlp_blocks, 256, 0, stream>>>(A, W1, b1, A, n_nodes);

    // ---- layer 2: agg(h1) -> out, mlp in-place out -> out ----
    gin_agg<<<agg_blocks, 256, 0, stream>>>((const float4*)A, offs, esrc, (float4*)out, n_nodes);
    gin_mlp<<<mlp_blocks, 256, 0, stream>>>(out, W2, b2, out, n_nodes);
}

// Round 6
// 196.407 us; speedup vs baseline: 2.4170x; 1.3465x over previous
//
#include <hip/hip_runtime.h>
#include <hip/hip_bf16.h>

// 2-layer GIN, pull-mode aggregation with bf16 neighbor gathers.
//   agg = f32(hb[n]) + sum f32(hb[src]);  h' = relu(agg @ W + b)
// Gathered feature matrix is bf16 (halves L2-miss traffic: 128B/row);
// accumulation and MLP stay fp32. CSR build = deterministic radix partition.
// Requires n_nodes < 2^18. Here N=100000, E=1600000, D=64.

#define D 64
#define ROWS_PER_BLOCK 32
#define CHSZ 8192      // edges per chunk (k1/k3)
#define NPBS 512       // nodes per super-bucket
#define SBSHIFT 9      // log2(NPBS)
#define MAXNBS 256     // static LDS cap on #super-buckets (n_nodes <= 131072)
#define MAXNCH 512     // static LDS cap on #chunks in k2c (n_edges <= 4.2M)

typedef unsigned short ushort_t;

__device__ inline unsigned short f2bf(float f) {   // RNE round to bf16
    unsigned u = __float_as_uint(f);
    return (unsigned short)((u + 0x7fff + ((u >> 16) & 1)) >> 16);
}

// acc[0..7] += 8 bf16 unpacked from one uint4
__device__ inline void acc8(float* acc, uint4 v) {
    acc[0] += __uint_as_float(v.x << 16);
    acc[1] += __uint_as_float(v.x & 0xffff0000u);
    acc[2] += __uint_as_float(v.y << 16);
    acc[3] += __uint_as_float(v.y & 0xffff0000u);
    acc[4] += __uint_as_float(v.z << 16);
    acc[5] += __uint_as_float(v.z & 0xffff0000u);
    acc[6] += __uint_as_float(v.w << 16);
    acc[7] += __uint_as_float(v.w & 0xffff0000u);
}

// ---------------- CSR build ----------------

__global__ __launch_bounds__(256) void k1_hist(const int* __restrict__ dst,
                                               int* __restrict__ hist,
                                               int n_edges, int nch, int nbs) {
    __shared__ int lh[MAXNBS];
    for (int i = threadIdx.x; i < nbs; i += 256) lh[i] = 0;
    __syncthreads();
    int base = blockIdx.x * CHSZ;
    int lim = min(CHSZ, n_edges - base);
    for (int k = threadIdx.x; k < lim; k += 256)
        atomicAdd(&lh[dst[base + k] >> SBSHIFT], 1);
    __syncthreads();
    for (int i = threadIdx.x; i < nbs; i += 256)
        hist[i * nch + blockIdx.x] = lh[i];   // bucket-major
}

__global__ __launch_bounds__(256) void k2a_rowsum(const int* __restrict__ hist,
                                                  int* __restrict__ total,
                                                  int nch, int nbs) {
    int w = threadIdx.x >> 6;
    int lane = threadIdx.x & 63;
    int b = blockIdx.x * 4 + w;
    if (b >= nbs) return;
    const int* row = hist + (size_t)b * nch;
    int s = 0;
    for (int c = lane; c < nch; c += 64) s += row[c];
#pragma unroll
    for (int off = 32; off > 0; off >>= 1) s += __shfl_down(s, off);
    if (lane == 0) total[b] = s;
}

__global__ __launch_bounds__(256) void k2b_scan(const int* __restrict__ total,
                                                int* __restrict__ sstart,
                                                int nbs, int n_edges) {
    __shared__ int t[256];
    int tid = threadIdx.x;
    t[tid] = (tid < nbs) ? total[tid] : 0;
    __syncthreads();
    for (int off = 1; off < 256; off <<= 1) {
        int v = (tid >= off) ? t[tid - off] : 0;
        __syncthreads();
        t[tid] += v;
        __syncthreads();
    }
    if (tid < nbs) sstart[tid] = (tid == 0) ? 0 : t[tid - 1];
    if (tid == 0) sstart[nbs] = n_edges;
}

__global__ __launch_bounds__(256) void k2c_rowscan(int* __restrict__ hist,
                                                   const int* __restrict__ sstart,
                                                   int nch, int nbs) {
    __shared__ int t[MAXNCH];
    int b = blockIdx.x;
    int tid = threadIdx.x;
    int* row = hist + (size_t)b * nch;
    int nround = (nch + 255) & ~255;
    for (int i = tid; i < nround; i += 256) t[i] = (i < nch) ? row[i] : 0;
    __syncthreads();
    for (int off = 1; off < nround; off <<= 1) {
        int v[MAXNCH / 256];
        for (int i = tid, j = 0; i < nround; i += 256, ++j)
            v[j] = (i >= off) ? t[i - off] : 0;
        __syncthreads();
        for (int i = tid, j = 0; i < nround; i += 256, ++j) t[i] += v[j];
        __syncthreads();
    }
    int base = sstart[b];
    for (int i = tid; i < nch; i += 256)
        row[i] = base + ((i == 0) ? 0 : t[i - 1]);
}

__global__ __launch_bounds__(256) void k3_scatter(const int* __restrict__ src,
                                                  const int* __restrict__ dst,
                                                  const int* __restrict__ hist,
                                                  unsigned* __restrict__ tmp,
                                                  int n_edges, int nch, int nbs) {
    __shared__ int lcur[MAXNBS];
    int c = blockIdx.x;
    for (int i = threadIdx.x; i < nbs; i += 256) lcur[i] = hist[i * nch + c];
    __syncthreads();
    int base = c * CHSZ;
    int lim = min(CHSZ, n_edges - base);
    for (int k = threadIdx.x; k < lim; k += 256) {
        int d = dst[base + k];
        int s = src[base + k];
        int pos = atomicAdd(&lcur[d >> SBSHIFT], 1);
        tmp[pos] = ((unsigned)(d & (NPBS - 1)) << 18) | (unsigned)s;
    }
}

__global__ __launch_bounds__(256) void k4_fine(const unsigned* __restrict__ tmp,
                                               const int* __restrict__ sstart,
                                               int* __restrict__ esrc,
                                               int* __restrict__ offs,
                                               int n_nodes) {
    __shared__ int lcnt[NPBS];
    __shared__ int lcur[NPBS];
    __shared__ int tsum[256];

    int b = blockIdx.x;
    int tid = threadIdx.x;
    int base = sstart[b];
    int cnt = sstart[b + 1] - base;

    lcnt[tid] = 0; lcnt[tid + 256] = 0;
    __syncthreads();

    for (int i = tid; i < cnt; i += 256)
        atomicAdd(&lcnt[tmp[base + i] >> 18], 1);
    __syncthreads();

    int a0 = lcnt[2 * tid], a1 = lcnt[2 * tid + 1];
    tsum[tid] = a0 + a1;
    __syncthreads();
    for (int off = 1; off < 256; off <<= 1) {
        int v = (tid >= off) ? tsum[tid - off] : 0;
        __syncthreads();
        tsum[tid] += v;
        __syncthreads();
    }
    int ex = (tid == 0) ? 0 : tsum[tid - 1];
    lcur[2 * tid] = ex;
    lcur[2 * tid + 1] = ex + a0;

    int node = b * NPBS + 2 * tid;
    if (node <= n_nodes) offs[node] = base + ex;
    if (node + 1 <= n_nodes) offs[node + 1] = base + ex + a0;
    __syncthreads();

    for (int i = tid; i < cnt; i += 256) {
        unsigned p = tmp[base + i];
        int pos = atomicAdd(&lcur[p >> 18], 1);
        esrc[base + pos] = (int)(p & 0x3FFFFu);
    }
}

// ---------------- per-layer kernels ----------------

// fp32 -> bf16 matrix conversion (RNE). n4 = count of float4 (= n_elems/4).
__global__ __launch_bounds__(256) void to_bf16(const float4* __restrict__ in,
                                               uint2* __restrict__ out, int n4) {
    int i = blockIdx.x * 256 + threadIdx.x;
    if (i >= n4) return;
    float4 v = in[i];
    out[i] = make_uint2((unsigned)f2bf(v.x) | ((unsigned)f2bf(v.y) << 16),
                        (unsigned)f2bf(v.z) | ((unsigned)f2bf(v.w) << 16));
}

// Pull aggregation over the bf16 matrix: 4 lanes/node, lane c owns bf16 cols
// [c*16, c*16+16) = 32 B = 2 uint4. acc starts at hb[n] (self term, eps=0).
// Output agg is fp32.
__global__ __launch_bounds__(256) void gin_agg_bf(const uint4* __restrict__ hb,
                                                  const int* __restrict__ offs,
                                                  const int* __restrict__ esrc,
                                                  float4* __restrict__ agg,
                                                  int n_nodes) {
    int t = blockIdx.x * 256 + threadIdx.x;
    int n = t >> 2;
    if (n >= n_nodes) return;
    int c = t & 3;
    const uint4* self = hb + (size_t)n * 8 + c * 2;   // row = 8 uint4 (128 B)
    float acc[16];
#pragma unroll
    for (int j = 0; j < 16; ++j) acc[j] = 0.0f;
    uint4 sv0 = self[0], sv1 = self[1];
    acc8(acc, sv0); acc8(acc + 8, sv1);

    int i = offs[n];
    int end = offs[n + 1];
    for (; i + 4 <= end; i += 4) {
        const uint4* r0 = hb + (size_t)esrc[i]     * 8 + c * 2;
        const uint4* r1 = hb + (size_t)esrc[i + 1] * 8 + c * 2;
        const uint4* r2 = hb + (size_t)esrc[i + 2] * 8 + c * 2;
        const uint4* r3 = hb + (size_t)esrc[i + 3] * 8 + c * 2;
        uint4 a0 = r0[0], b0 = r0[1];
        uint4 a1 = r1[0], b1 = r1[1];
        uint4 a2 = r2[0], b2 = r2[1];
        uint4 a3 = r3[0], b3 = r3[1];
        acc8(acc, a0); acc8(acc + 8, b0);
        acc8(acc, a1); acc8(acc + 8, b1);
        acc8(acc, a2); acc8(acc + 8, b2);
        acc8(acc, a3); acc8(acc + 8, b3);
    }
    for (; i < end; ++i) {
        const uint4* r = hb + (size_t)esrc[i] * 8 + c * 2;
        uint4 a = r[0], b = r[1];
        acc8(acc, a); acc8(acc + 8, b);
    }

    float4* o = agg + (size_t)n * 16 + c * 4;
    o[0] = make_float4(acc[0], acc[1], acc[2], acc[3]);
    o[1] = make_float4(acc[4], acc[5], acc[6], acc[7]);
    o[2] = make_float4(acc[8], acc[9], acc[10], acc[11]);
    o[3] = make_float4(acc[12], acc[13], acc[14], acc[15]);
}

// out = relu(hs @ W + b); BF16OUT selects bf16 (ushort) or fp32 output.
template <bool BF16OUT>
__global__ __launch_bounds__(256) void gin_mlp(const float* __restrict__ hs,
                                               const float* __restrict__ W,
                                               const float* __restrict__ b,
                                               void* __restrict__ out_,
                                               int n_nodes) {
    __shared__ float Wl[D * D];
    __shared__ float bl[D];
    __shared__ float rows[ROWS_PER_BLOCK][D];

    int tid = threadIdx.x;

    const float4* W4 = (const float4*)W;
    float4* Wl4 = (float4*)Wl;
#pragma unroll
    for (int i = 0; i < 4; ++i) Wl4[tid + 256 * i] = W4[tid + 256 * i];
    if (tid < D / 4) ((float4*)bl)[tid] = ((const float4*)b)[tid];

    size_t row0 = (size_t)blockIdx.x * ROWS_PER_BLOCK;
    const float4* hs4 = (const float4*)(hs + row0 * D);
    float4* rows4 = (float4*)rows;
#pragma unroll
    for (int i = 0; i < 2; ++i) rows4[tid + 256 * i] = hs4[tid + 256 * i];

    __syncthreads();

    int lane = tid & 63;
    int w = tid >> 6;

    float acc[8];
#pragma unroll
    for (int r = 0; r < 8; ++r) acc[r] = bl[lane];

#pragma unroll
    for (int k = 0; k < D; ++k) {
        float wv = Wl[k * D + lane];
#pragma unroll
        for (int r = 0; r < 8; ++r)
            acc[r] = fmaf(rows[w * 8 + r][k], wv, acc[r]);
    }

#pragma unroll
    for (int r = 0; r < 8; ++r) {
        float v = acc[r] > 0.0f ? acc[r] : 0.0f;
        size_t idx = (row0 + (size_t)w * 8 + r) * D + lane;
        if (BF16OUT) ((ushort_t*)out_)[idx] = f2bf(v);
        else         ((float*)out_)[idx] = v;
    }
}

extern "C" void kernel_launch(void* const* d_in, const int* in_sizes, int n_in,
                              void* d_out, int out_size, void* d_ws, size_t ws_size,
                              hipStream_t stream) {
    const float* x   = (const float*)d_in[0];
    const int*   src = (const int*)d_in[1];
    const int*   dst = (const int*)d_in[2];
    const float* W1  = (const float*)d_in[3];
    const float* b1  = (const float*)d_in[4];
    const float* W2  = (const float*)d_in[5];
    const float* b2  = (const float*)d_in[6];
    float* out = (float*)d_out;

    const int n_nodes = in_sizes[0] / D;
    const int n_edges = in_sizes[1];
    const int nch = (n_edges + CHSZ - 1) / CHSZ;     // 196
    const int nbs = (n_nodes + NPBS - 1) / NPBS;     // 196

    // workspace: A(f32) | hb(bf16, reused for xb then h1b) | offs | sstart |
    //            total | hist | tmp | esrc   (~52 MB)
    float*    A      = (float*)d_ws;                        // n_nodes*64 f32
    ushort_t* hb     = (ushort_t*)(A + (size_t)n_nodes * D);// n_nodes*64 bf16
    int*      offs   = (int*)(hb + (size_t)n_nodes * D);    // n_nodes+1
    int*      sstart = offs + (n_nodes + 1);                // nbs+1
    int*      total  = sstart + (nbs + 1);                  // nbs
    int*      hist   = total + nbs;                         // nbs*nch
    unsigned* tmp    = (unsigned*)(hist + (size_t)nbs * nch); // n_edges
    int*      esrc   = (int*)(tmp + n_edges);               // n_edges

    const int agg_blocks = (n_nodes * 4 + 255) / 256;
    const int mlp_blocks = (n_nodes + ROWS_PER_BLOCK - 1) / ROWS_PER_BLOCK;
    const int cvt_blocks = (n_nodes * (D / 4) + 255) / 256;

    // ---- CSR build (deterministic, no global atomics) ----
    k1_hist<<<nch, 256, 0, stream>>>(dst, hist, n_edges, nch, nbs);
    k2a_rowsum<<<(nbs + 3) / 4, 256, 0, stream>>>(hist, total, nch, nbs);
    k2b_scan<<<1, 256, 0, stream>>>(total, sstart, nbs, n_edges);
    k2c_rowscan<<<nbs, 256, 0, stream>>>(hist, sstart, nch, nbs);
    k3_scatter<<<nch, 256, 0, stream>>>(src, dst, hist, tmp, n_edges, nch, nbs);
    k4_fine<<<nbs, 256, 0, stream>>>(tmp, sstart, esrc, offs, n_nodes);

    // ---- layer 1: xb = bf16(x); agg(xb) -> A; mlp(A) -> hb (bf16 h1) ----
    to_bf16<<<cvt_blocks, 256, 0, stream>>>((const float4*)x, (uint2*)hb,
                                            n_nodes * (D / 4));
    gin_agg_bf<<<agg_blocks, 256, 0, stream>>>((const uint4*)hb, offs, esrc,
                                               (float4*)A, n_nodes);
    gin_mlp<true><<<mlp_blocks, 256, 0, stream>>>(A, W1, b1, hb, n_nodes);

    // ---- layer 2: agg(h1b) -> A; mlp(A) -> out (fp32) ----
    gin_agg_bf<<<agg_blocks, 256, 0, stream>>>((const uint4*)hb, offs, esrc,
                                               (float4*)A, n_nodes);
    gin_mlp<false><<<mlp_blocks, 256, 0, stream>>>(A, W2, b2, out, n_nodes);
}